// Round 5
// baseline (1086.964 us; speedup 1.0000x reference)
//
#include <hip/hip_runtime.h>
#include <math.h>

#define N_NEU    2048
#define BB       64
#define TT       100
#define KIN      784
#define NIN_NEU  1024
#define N_OUT    10
#define NOUT_NEU 128

typedef unsigned int u32;
typedef unsigned long long u64;
typedef unsigned short u16;

// ---------------- prep ----------------
__global__ void k_prep(const float* __restrict__ tau, double* __restrict__ d_syn,
                       double* __restrict__ e_tau){
    int n = blockIdx.x * blockDim.x + threadIdx.x;
    if(n < N_NEU){
        double tv = (double)tau[n];
        d_syn[n] = exp(-1.0 / tv);
        e_tau[n] = 2.718281828459045 / tv;   // np.e / tau
    }
}

// zero projG (ws is poisoned 0xAA)
__global__ void k_zero(double* __restrict__ p, long nels){
    long i = (long)blockIdx.x * blockDim.x + threadIdx.x;
    long stride = (long)gridDim.x * blockDim.x;
    for(; i < nels; i += stride) p[i] = 0.0;
}

// ---------------- W transpose: Wt[m][n] = Wrec[n][m] ----------------
__global__ __launch_bounds__(256) void k_tr(const float* __restrict__ Wrec, float* __restrict__ Wt){
    __shared__ float tile[32][33];
    int bx = blockIdx.x, by = blockIdx.y;
    int txx = threadIdx.x, tyy = threadIdx.y;          // (32, 8)
    #pragma unroll
    for(int j=0;j<4;j++)
        tile[tyy+8*j][txx] = Wrec[(size_t)(by*32 + tyy+8*j)*N_NEU + bx*32 + txx];
    __syncthreads();
    #pragma unroll
    for(int j=0;j<4;j++)
        Wt[(size_t)(bx*32 + tyy+8*j)*N_NEU + by*32 + txx] = tile[txx][tyy+8*j];
}

// ---------------- input projection GEMM (fp64 accum, fp32 LDS) ----------------
// projG[b][t][iidx[c]] = sum_k X[t*64+b][k] * Win[c][k]   (other n stay zero)
__global__ __launch_bounds__(256) void k_proj(const float* __restrict__ X, const float* __restrict__ Win,
                                              const int* __restrict__ iidx, double* __restrict__ projG){
    __shared__ float As[32][68];
    __shared__ float Bs[32][68];
    const int r0 = blockIdx.x * 64;          // 64 rows == one t
    const int c0 = blockIdx.y * 64;
    const int t  = threadIdx.x;
    const int lr = t >> 2;          // 0..63
    const int lk = (t & 3) * 8;     // 0,8,16,24
    const int tx = t & 15, ty = t >> 4;
    double acc[4][4] = {};
    for(int k0 = 0; k0 < KIN; k0 += 32){
        int kk = k0 + lk;
        float a8[8], b8[8];
        if(kk + 8 <= KIN){
            const float* pa = X   + (size_t)(r0+lr)*KIN + kk;
            const float* pb = Win + (size_t)(c0+lr)*KIN + kk;
            float4 ra0 = *reinterpret_cast<const float4*>(pa);
            float4 ra1 = *reinterpret_cast<const float4*>(pa + 4);
            float4 rb0 = *reinterpret_cast<const float4*>(pb);
            float4 rb1 = *reinterpret_cast<const float4*>(pb + 4);
            a8[0]=ra0.x; a8[1]=ra0.y; a8[2]=ra0.z; a8[3]=ra0.w;
            a8[4]=ra1.x; a8[5]=ra1.y; a8[6]=ra1.z; a8[7]=ra1.w;
            b8[0]=rb0.x; b8[1]=rb0.y; b8[2]=rb0.z; b8[3]=rb0.w;
            b8[4]=rb1.x; b8[5]=rb1.y; b8[6]=rb1.z; b8[7]=rb1.w;
        } else {
            #pragma unroll
            for(int e=0;e<8;e++){ a8[e]=0.0f; b8[e]=0.0f; }
        }
        #pragma unroll
        for(int e=0;e<8;e++){ As[lk+e][lr] = a8[e]; Bs[lk+e][lr] = b8[e]; }
        __syncthreads();
        #pragma unroll
        for(int kkk=0;kkk<32;kkk++){
            float4 af = *reinterpret_cast<const float4*>(&As[kkk][ty*4]);
            float4 bf = *reinterpret_cast<const float4*>(&Bs[kkk][tx*4]);
            double a[4] = {(double)af.x,(double)af.y,(double)af.z,(double)af.w};
            double b[4] = {(double)bf.x,(double)bf.y,(double)bf.z,(double)bf.w};
            #pragma unroll
            for(int i=0;i<4;i++)
                #pragma unroll
                for(int j=0;j<4;j++)
                    acc[i][j] += a[i]*b[j];
        }
        __syncthreads();
    }
    const int tt = blockIdx.x;
    #pragma unroll
    for(int j=0;j<4;j++){
        int c = c0 + tx*4 + j;
        int n = iidx[c];
        #pragma unroll
        for(int i=0;i<4;i++){
            int b = ty*4 + i;
            projG[((size_t)b*TT + tt)*N_NEU + n] = acc[i][j];
        }
    }
}

__device__ __forceinline__ u32 spread16(u32 x){
    x = (x | (x << 8)) & 0x00FF00FFu;
    x = (x | (x << 4)) & 0x0F0F0F0Fu;
    x = (x | (x << 2)) & 0x33333333u;
    x = (x | (x << 1)) & 0x55555555u;
    return x;
}

// ---------------- per-batch simulation: 64 blocks x 1024 threads ----------------
// Block b owns batch b. Thread owns neurons n0=2*tid, n1=2*tid+1. No grid sync.
__global__ __launch_bounds__(1024) void k_sim(
        const double* __restrict__ projG, const float* __restrict__ Wt,
        const double* __restrict__ dsyn, const double* __restrict__ etau,
        double* __restrict__ cntout){
    __shared__ u32 words[64];
    __shared__ u16 list[N_NEU];
    __shared__ int cntS;

    const int b   = blockIdx.x;
    const int tid = threadIdx.x;
    const int n0 = tid*2, n1 = tid*2 + 1;
    const double* projB = projG + (size_t)b * TT * N_NEU;

    const double ds0 = dsyn[n0], et0 = etau[n0];
    const double ds1 = dsyn[n1], et1 = etau[n1];
    const double dasc = exp(-0.0125);

    double v0=-60.0, psc0=0.0, rise0=0.0, asc0=0.0, ref0=0.0, s0=0.0, c0=0.0;
    double v1=-60.0, psc1=0.0, rise1=0.0, asc1=0.0, ref1=0.0, s1=0.0, c1=0.0;

    if(tid == 0) cntS = 0;
    __syncthreads();

    for(int t=0;t<TT;t++){
        // coalesced per-step external drive (exact fp64 from projection GEMM)
        double2 pp = *reinterpret_cast<const double2*>(projB + (size_t)t*N_NEU + n0);

        // ---- gather recurrent input over ordered spike list (ascending m) ----
        double I0 = 0.0, I1 = 0.0;
        const int cc = cntS;
        int i = 0;
        for(; i + 8 <= cc; i += 8){
            int m[8];
            #pragma unroll
            for(int u=0;u<8;u++) m[u] = list[i+u];
            float2 wv[8];
            #pragma unroll
            for(int u=0;u<8;u++)
                wv[u] = *reinterpret_cast<const float2*>(Wt + ((size_t)m[u] << 11) + n0);
            #pragma unroll
            for(int u=0;u<8;u++){ I0 += (double)wv[u].x; I1 += (double)wv[u].y; }
        }
        for(; i < cc; ++i){
            int mm = list[i];
            float2 w = *reinterpret_cast<const float2*>(Wt + ((size_t)mm << 11) + n0);
            I0 += (double)w.x; I1 += (double)w.y;
        }
        I0 += pp.x; I1 += pp.y;

        // ---- neuron updates (verified arithmetic, unchanged order) ----
        double psc_n0  = ds0 * (psc0 + rise0);
        double rise_n0 = ds0 * rise0 + et0 * I0;
        double asc_n0  = dasc * asc0 + (-0.2) * s0;
        double act0    = (ref0 <= 0.0) ? 1.0 : 0.0;
        double dv0  = (psc_n0 + asc_n0 + 0.12) / 2.0 - (v0 - (-60.0)) / 20.0;
        double v_n0 = v0 + act0 * dv0;
        double s_n0 = ((v_n0 - (-45.0)) >= 0.0) ? act0 : 0.0;
        v_n0 = v_n0 - s_n0 * 15.0;
        double ref_n0 = (s_n0 > 0.0) ? 2.0 : fmax(ref0 - 1.0, 0.0);
        v0 = v_n0; psc0 = psc_n0; rise0 = rise_n0; asc0 = asc_n0; ref0 = ref_n0; s0 = s_n0;
        c0 += s_n0;

        double psc_n1  = ds1 * (psc1 + rise1);
        double rise_n1 = ds1 * rise1 + et1 * I1;
        double asc_n1  = dasc * asc1 + (-0.2) * s1;
        double act1    = (ref1 <= 0.0) ? 1.0 : 0.0;
        double dv1  = (psc_n1 + asc_n1 + 0.12) / 2.0 - (v1 - (-60.0)) / 20.0;
        double v_n1 = v1 + act1 * dv1;
        double s_n1 = ((v_n1 - (-45.0)) >= 0.0) ? act1 : 0.0;
        v_n1 = v_n1 - s_n1 * 15.0;
        double ref_n1 = (s_n1 > 0.0) ? 2.0 : fmax(ref1 - 1.0, 0.0);
        v1 = v_n1; psc1 = psc_n1; rise1 = rise_n1; asc1 = asc_n1; ref1 = ref_n1; s1 = s_n1;
        c1 += s_n1;

        // ---- publish spikes: interleave even/odd ballots into neuron-order bitmask ----
        u64 bal0 = __ballot(s_n0 > 0.0);   // neuron 128W + 2k   (k = lane)
        u64 bal1 = __ballot(s_n1 > 0.0);   // neuron 128W + 2k+1
        int lane = tid & 63;
        if(lane < 4){
            u32 e = (u32)((bal0 >> (16*lane)) & 0xffffULL);
            u32 o = (u32)((bal1 >> (16*lane)) & 0xffffULL);
            words[(tid >> 6)*4 + lane] = spread16(e) | (spread16(o) << 1);
        }
        __syncthreads();

        // ---- wave 0: ordered compaction into list (ascending neuron index) ----
        if(tid < 64){
            u32 wv = words[tid];
            int c = __popc(wv);
            int incl = c;
            #pragma unroll
            for(int off=1; off<64; off<<=1){
                int x = __shfl_up(incl, off);
                if(tid >= off) incl += x;
            }
            int excl = incl - c;
            u32 z = wv;
            int base = tid * 32;
            while(z){
                int bp = __ffs(z) - 1;
                z &= z - 1;
                list[excl++] = (u16)(base + bp);
            }
            if(tid == 63) cntS = incl;
        }
        __syncthreads();
    }

    cntout[(size_t)b*N_NEU + n0] = c0;
    cntout[(size_t)b*N_NEU + n1] = c1;
}

// ---------------- readout ----------------
__global__ void k_final(const double* __restrict__ cnt, const int* __restrict__ oidx,
                        const float* __restrict__ Wout, float* __restrict__ out){
    int i = blockIdx.x * blockDim.x + threadIdx.x;
    if(i >= BB * N_OUT) return;
    int b = i / N_OUT, o = i - b * N_OUT;
    double accv = 0.0;
    for(int j=0;j<NOUT_NEU;j++){
        double rate = cnt[(size_t)b*N_NEU + oidx[j]] / 100.0;
        accv += rate * (double)Wout[o*NOUT_NEU + j];
    }
    out[i] = (float)accv;
}

extern "C" void kernel_launch(void* const* d_in, const int* in_sizes, int n_in,
                              void* d_out, int out_size, void* d_ws, size_t ws_size,
                              hipStream_t stream){
    const float* X    = (const float*)d_in[0];
    const float* Win  = (const float*)d_in[1];
    const float* Wrec = (const float*)d_in[2];
    const float* Wout = (const float*)d_in[3];
    const float* tau  = (const float*)d_in[4];
    const int*   iidx = (const int*)d_in[5];
    const int*   oidx = (const int*)d_in[6];
    float* out = (float*)d_out;

    char* w = (char*)d_ws;
    const size_t OFF_PROJG = 0;                                     // 104,857,600
    const size_t OFF_CNT   = OFF_PROJG + (size_t)BB*TT*N_NEU*8;     // 1,048,576
    const size_t OFF_WT    = OFF_CNT + (size_t)BB*N_NEU*8;          // 16,777,216
    const size_t OFF_DS    = OFF_WT + (size_t)N_NEU*N_NEU*4;
    const size_t OFF_ET    = OFF_DS + N_NEU*8;

    double* projG = (double*)(w + OFF_PROJG);
    double* cnt   = (double*)(w + OFF_CNT);
    float*  Wt    = (float*)(w + OFF_WT);
    double* dsyn  = (double*)(w + OFF_DS);
    double* etau  = (double*)(w + OFF_ET);

    k_prep <<<dim3(8),      dim3(256),  0, stream>>>(tau, dsyn, etau);
    k_zero <<<dim3(4096),   dim3(256),  0, stream>>>(projG, (long)BB*TT*N_NEU);
    k_tr   <<<dim3(64,64),  dim3(32,8), 0, stream>>>(Wrec, Wt);
    k_proj <<<dim3(100,16), dim3(256),  0, stream>>>(X, Win, iidx, projG);
    k_sim  <<<dim3(BB),     dim3(1024), 0, stream>>>(projG, Wt, dsyn, etau, cnt);
    k_final<<<dim3(3),      dim3(256),  0, stream>>>(cnt, oidx, Wout, out);
}

// Round 6
// 925.982 us; speedup vs baseline: 1.1739x; 1.1739x over previous
//
#include <hip/hip_runtime.h>
#include <math.h>

#define N_NEU    2048
#define BB       64
#define TT       100
#define KIN      784
#define NIN_NEU  1024
#define N_OUT    10
#define NOUT_NEU 128

typedef unsigned int u32;
typedef unsigned long long u64;
typedef unsigned short u16;

// ---------------- prep ----------------
__global__ void k_prep(const float* __restrict__ tau, double* __restrict__ d_syn,
                       double* __restrict__ e_tau){
    int n = blockIdx.x * blockDim.x + threadIdx.x;
    if(n < N_NEU){
        double tv = (double)tau[n];
        d_syn[n] = exp(-1.0 / tv);
        e_tau[n] = 2.718281828459045 / tv;   // np.e / tau
    }
}

// zero projG (ws is poisoned 0xAA)
__global__ void k_zero(double* __restrict__ p, long nels){
    long i = (long)blockIdx.x * blockDim.x + threadIdx.x;
    long stride = (long)gridDim.x * blockDim.x;
    for(; i < nels; i += stride) p[i] = 0.0;
}

// ---------------- W transpose: Wt[m][n] = Wrec[n][m] ----------------
__global__ __launch_bounds__(256) void k_tr(const float* __restrict__ Wrec, float* __restrict__ Wt){
    __shared__ float tile[32][33];
    int bx = blockIdx.x, by = blockIdx.y;
    int txx = threadIdx.x, tyy = threadIdx.y;          // (32, 8)
    #pragma unroll
    for(int j=0;j<4;j++)
        tile[tyy+8*j][txx] = Wrec[(size_t)(by*32 + tyy+8*j)*N_NEU + bx*32 + txx];
    __syncthreads();
    #pragma unroll
    for(int j=0;j<4;j++)
        Wt[(size_t)(bx*32 + tyy+8*j)*N_NEU + by*32 + txx] = tile[txx][tyy+8*j];
}

// ---------------- input projection GEMM (fp64 accum, fp32 LDS) ----------------
// projG[b][t][iidx[c]] = sum_k X[t*64+b][k] * Win[c][k]   (other n stay zero)
__global__ __launch_bounds__(256) void k_proj(const float* __restrict__ X, const float* __restrict__ Win,
                                              const int* __restrict__ iidx, double* __restrict__ projG){
    __shared__ float As[32][68];
    __shared__ float Bs[32][68];
    const int r0 = blockIdx.x * 64;          // 64 rows == one t
    const int c0 = blockIdx.y * 64;
    const int t  = threadIdx.x;
    const int lr = t >> 2;          // 0..63
    const int lk = (t & 3) * 8;     // 0,8,16,24
    const int tx = t & 15, ty = t >> 4;
    double acc[4][4] = {};
    for(int k0 = 0; k0 < KIN; k0 += 32){
        int kk = k0 + lk;
        float a8[8], b8[8];
        if(kk + 8 <= KIN){
            const float* pa = X   + (size_t)(r0+lr)*KIN + kk;
            const float* pb = Win + (size_t)(c0+lr)*KIN + kk;
            float4 ra0 = *reinterpret_cast<const float4*>(pa);
            float4 ra1 = *reinterpret_cast<const float4*>(pa + 4);
            float4 rb0 = *reinterpret_cast<const float4*>(pb);
            float4 rb1 = *reinterpret_cast<const float4*>(pb + 4);
            a8[0]=ra0.x; a8[1]=ra0.y; a8[2]=ra0.z; a8[3]=ra0.w;
            a8[4]=ra1.x; a8[5]=ra1.y; a8[6]=ra1.z; a8[7]=ra1.w;
            b8[0]=rb0.x; b8[1]=rb0.y; b8[2]=rb0.z; b8[3]=rb0.w;
            b8[4]=rb1.x; b8[5]=rb1.y; b8[6]=rb1.z; b8[7]=rb1.w;
        } else {
            #pragma unroll
            for(int e=0;e<8;e++){ a8[e]=0.0f; b8[e]=0.0f; }
        }
        #pragma unroll
        for(int e=0;e<8;e++){ As[lk+e][lr] = a8[e]; Bs[lk+e][lr] = b8[e]; }
        __syncthreads();
        #pragma unroll
        for(int kkk=0;kkk<32;kkk++){
            float4 af = *reinterpret_cast<const float4*>(&As[kkk][ty*4]);
            float4 bf = *reinterpret_cast<const float4*>(&Bs[kkk][tx*4]);
            double a[4] = {(double)af.x,(double)af.y,(double)af.z,(double)af.w};
            double b[4] = {(double)bf.x,(double)bf.y,(double)bf.z,(double)bf.w};
            #pragma unroll
            for(int i=0;i<4;i++)
                #pragma unroll
                for(int j=0;j<4;j++)
                    acc[i][j] += a[i]*b[j];
        }
        __syncthreads();
    }
    const int tt = blockIdx.x;
    #pragma unroll
    for(int j=0;j<4;j++){
        int c = c0 + tx*4 + j;
        int n = iidx[c];
        #pragma unroll
        for(int i=0;i<4;i++){
            int b = ty*4 + i;
            projG[((size_t)b*TT + tt)*N_NEU + n] = acc[i][j];
        }
    }
}

__device__ __forceinline__ u32 spread16(u32 x){
    x = (x | (x << 8)) & 0x00FF00FFu;
    x = (x | (x << 4)) & 0x0F0F0F0Fu;
    x = (x | (x << 2)) & 0x33333333u;
    x = (x | (x << 1)) & 0x55555555u;
    return x;
}

// ---------------- per-batch simulation: 64 blocks x 1024 threads ----------------
// Block b owns batch b. Gather phase: thread=(half,q) sums its half of the spike
// list for neurons 4q..4q+3 (float4 rows) into LDS partials Ip[2][2048].
// Update phase: thread tid owns neurons 2tid, 2tid+1. No grid sync.
__global__ __launch_bounds__(1024) void k_sim(
        const double* __restrict__ projG, const float* __restrict__ Wt,
        const double* __restrict__ dsyn, const double* __restrict__ etau,
        double* __restrict__ cntout){
    __shared__ double Ip[2][N_NEU];   // 32 KB partial currents
    __shared__ u32 words[64];
    __shared__ u16 list[N_NEU];
    __shared__ int cntS;

    const int b   = blockIdx.x;
    const int tid = threadIdx.x;
    const int n0 = tid*2, n1 = tid*2 + 1;
    const int half = tid >> 9;        // which list chunk this thread sums
    const int nq   = (tid & 511) * 4; // first of 4 neurons this thread gathers for
    const double* projB = projG + (size_t)b * TT * N_NEU;

    const double ds0 = dsyn[n0], et0 = etau[n0];
    const double ds1 = dsyn[n1], et1 = etau[n1];
    const double dasc = exp(-0.0125);

    double v0=-60.0, psc0=0.0, rise0=0.0, asc0=0.0, ref0=0.0, s0=0.0, c0=0.0;
    double v1=-60.0, psc1=0.0, rise1=0.0, asc1=0.0, ref1=0.0, s1=0.0, c1=0.0;

    if(tid == 0) cntS = 0;
    __syncthreads();

    for(int t=0;t<TT;t++){
        // coalesced per-step external drive (exact fp64 from projection GEMM)
        double2 pp = *reinterpret_cast<const double2*>(projB + (size_t)t*N_NEU + n0);

        // ---- gather: sum my half of the spike list for 4 neurons ----
        const int cc = cntS;
        const int h  = cc >> 1;
        const int beg = half ? h  : 0;
        const int end = half ? cc : h;
        double I[4] = {0.0, 0.0, 0.0, 0.0};
        int i = beg;
        for(; i + 8 <= end; i += 8){
            int m[8];
            #pragma unroll
            for(int u=0;u<8;u++) m[u] = list[i+u];
            float4 wv[8];
            #pragma unroll
            for(int u=0;u<8;u++)
                wv[u] = *reinterpret_cast<const float4*>(Wt + ((size_t)m[u] << 11) + nq);
            #pragma unroll
            for(int u=0;u<8;u++){
                I[0] += (double)wv[u].x; I[1] += (double)wv[u].y;
                I[2] += (double)wv[u].z; I[3] += (double)wv[u].w;
            }
        }
        for(; i < end; ++i){
            int mm = list[i];
            float4 w4 = *reinterpret_cast<const float4*>(Wt + ((size_t)mm << 11) + nq);
            I[0] += (double)w4.x; I[1] += (double)w4.y;
            I[2] += (double)w4.z; I[3] += (double)w4.w;
        }
        #pragma unroll
        for(int u=0;u<4;u++) Ip[half][nq+u] = I[u];
        __syncthreads();

        // ---- combine partials: fixed order chunk0 + chunk1, then + proj ----
        double I0 = Ip[0][n0] + Ip[1][n0] + pp.x;
        double I1 = Ip[0][n1] + Ip[1][n1] + pp.y;

        // ---- neuron updates (verified arithmetic) ----
        double psc_n0  = ds0 * (psc0 + rise0);
        double rise_n0 = ds0 * rise0 + et0 * I0;
        double asc_n0  = dasc * asc0 + (-0.2) * s0;
        double act0    = (ref0 <= 0.0) ? 1.0 : 0.0;
        double dv0  = (psc_n0 + asc_n0 + 0.12) / 2.0 - (v0 - (-60.0)) / 20.0;
        double v_n0 = v0 + act0 * dv0;
        double s_n0 = ((v_n0 - (-45.0)) >= 0.0) ? act0 : 0.0;
        v_n0 = v_n0 - s_n0 * 15.0;
        double ref_n0 = (s_n0 > 0.0) ? 2.0 : fmax(ref0 - 1.0, 0.0);
        v0 = v_n0; psc0 = psc_n0; rise0 = rise_n0; asc0 = asc_n0; ref0 = ref_n0; s0 = s_n0;
        c0 += s_n0;

        double psc_n1  = ds1 * (psc1 + rise1);
        double rise_n1 = ds1 * rise1 + et1 * I1;
        double asc_n1  = dasc * asc1 + (-0.2) * s1;
        double act1    = (ref1 <= 0.0) ? 1.0 : 0.0;
        double dv1  = (psc_n1 + asc_n1 + 0.12) / 2.0 - (v1 - (-60.0)) / 20.0;
        double v_n1 = v1 + act1 * dv1;
        double s_n1 = ((v_n1 - (-45.0)) >= 0.0) ? act1 : 0.0;
        v_n1 = v_n1 - s_n1 * 15.0;
        double ref_n1 = (s_n1 > 0.0) ? 2.0 : fmax(ref1 - 1.0, 0.0);
        v1 = v_n1; psc1 = psc_n1; rise1 = rise_n1; asc1 = asc_n1; ref1 = ref_n1; s1 = s_n1;
        c1 += s_n1;

        // ---- publish spikes: interleave even/odd ballots into neuron-order bitmask ----
        u64 bal0 = __ballot(s_n0 > 0.0);   // neuron 128W + 2k   (k = lane)
        u64 bal1 = __ballot(s_n1 > 0.0);   // neuron 128W + 2k+1
        int lane = tid & 63;
        if(lane < 4){
            u32 e = (u32)((bal0 >> (16*lane)) & 0xffffULL);
            u32 o = (u32)((bal1 >> (16*lane)) & 0xffffULL);
            words[(tid >> 6)*4 + lane] = spread16(e) | (spread16(o) << 1);
        }
        __syncthreads();

        // ---- wave 0: ordered compaction into list (ascending neuron index) ----
        if(tid < 64){
            u32 wv = words[tid];
            int c = __popc(wv);
            int incl = c;
            #pragma unroll
            for(int off=1; off<64; off<<=1){
                int x = __shfl_up(incl, off);
                if(tid >= off) incl += x;
            }
            int excl = incl - c;
            u32 z = wv;
            int base = tid * 32;
            while(z){
                int bp = __ffs(z) - 1;
                z &= z - 1;
                list[excl++] = (u16)(base + bp);
            }
            if(tid == 63) cntS = incl;
        }
        __syncthreads();
    }

    cntout[(size_t)b*N_NEU + n0] = c0;
    cntout[(size_t)b*N_NEU + n1] = c1;
}

// ---------------- readout ----------------
__global__ void k_final(const double* __restrict__ cnt, const int* __restrict__ oidx,
                        const float* __restrict__ Wout, float* __restrict__ out){
    int i = blockIdx.x * blockDim.x + threadIdx.x;
    if(i >= BB * N_OUT) return;
    int b = i / N_OUT, o = i - b * N_OUT;
    double accv = 0.0;
    for(int j=0;j<NOUT_NEU;j++){
        double rate = cnt[(size_t)b*N_NEU + oidx[j]] / 100.0;
        accv += rate * (double)Wout[o*NOUT_NEU + j];
    }
    out[i] = (float)accv;
}

extern "C" void kernel_launch(void* const* d_in, const int* in_sizes, int n_in,
                              void* d_out, int out_size, void* d_ws, size_t ws_size,
                              hipStream_t stream){
    const float* X    = (const float*)d_in[0];
    const float* Win  = (const float*)d_in[1];
    const float* Wrec = (const float*)d_in[2];
    const float* Wout = (const float*)d_in[3];
    const float* tau  = (const float*)d_in[4];
    const int*   iidx = (const int*)d_in[5];
    const int*   oidx = (const int*)d_in[6];
    float* out = (float*)d_out;

    char* w = (char*)d_ws;
    const size_t OFF_PROJG = 0;                                     // 104,857,600
    const size_t OFF_CNT   = OFF_PROJG + (size_t)BB*TT*N_NEU*8;     // 1,048,576
    const size_t OFF_WT    = OFF_CNT + (size_t)BB*N_NEU*8;          // 16,777,216
    const size_t OFF_DS    = OFF_WT + (size_t)N_NEU*N_NEU*4;
    const size_t OFF_ET    = OFF_DS + N_NEU*8;

    double* projG = (double*)(w + OFF_PROJG);
    double* cnt   = (double*)(w + OFF_CNT);
    float*  Wt    = (float*)(w + OFF_WT);
    double* dsyn  = (double*)(w + OFF_DS);
    double* etau  = (double*)(w + OFF_ET);

    k_prep <<<dim3(8),      dim3(256),  0, stream>>>(tau, dsyn, etau);
    k_zero <<<dim3(4096),   dim3(256),  0, stream>>>(projG, (long)BB*TT*N_NEU);
    k_tr   <<<dim3(64,64),  dim3(32,8), 0, stream>>>(Wrec, Wt);
    k_proj <<<dim3(100,16), dim3(256),  0, stream>>>(X, Win, iidx, projG);
    k_sim  <<<dim3(BB),     dim3(1024), 0, stream>>>(projG, Wt, dsyn, etau, cnt);
    k_final<<<dim3(3),      dim3(256),  0, stream>>>(cnt, oidx, Wout, out);
}